// Round 7
// baseline (1072.360 us; speedup 1.0000x reference)
//
#include <hip/hip_runtime.h>
#include <hip/hip_bf16.h>
#include <math.h>

typedef __hip_bfloat16 bf16;
typedef _Float16 f16;
typedef __attribute__((ext_vector_type(8))) _Float16 f16x8;
typedef __attribute__((ext_vector_type(4))) _Float16 f16x4;
typedef __attribute__((ext_vector_type(4))) float f32x4;

#define B_ 32
#define HW_ 784
#define T_ 785
#define TP_ 197
#define C_ 384
#define H_ 8
#define D_ 48
#define FF_ 1536

#define MFMA16(a, b, c) __builtin_amdgcn_mfma_f32_16x16x32_f16(a, b, c, 0, 0, 0)

// ---------------- sizes (elements) ----------------
static constexpr size_t NRES = (size_t)B_ * T_ * C_;
static constexpr size_t NX   = (size_t)B_ * HW_ * C_;
static constexpr size_t NCLS = (size_t)B_ * C_;
static constexpr size_t NLN1 = (size_t)T_ * C_;
static constexpr size_t NWP  = (size_t)C_ * C_;
static constexpr size_t NLN2 = (size_t)TP_ * C_;
static constexpr size_t NW1  = (size_t)FF_ * C_;
static constexpr size_t NX2  = (size_t)B_ * TP_ * C_;
static constexpr size_t NH   = (size_t)B_ * TP_ * FF_;

// frag-major plane sizes (halfs)
static constexpr size_t NX1F = (size_t)1576 * 12 * 512;   // M1 rows padded to 25216
static constexpr size_t NQKF = (size_t)256 * 56 * 2 * 512; // per-bh 56 t-tiles x 2 kc
static constexpr size_t NVF  = (size_t)256 * 3 * 25 * 512; // per-bh 25 kc x 3 d-tiles
static constexpr size_t NX2F = (size_t)400 * 12 * 512;     // M2 rows padded to 6400
static constexpr size_t NHF  = (size_t)400 * 48 * 512;

// ---------------- arena byte offsets ----------------
static constexpr size_t XF_OFF   = 0;
static constexpr size_t CLSF_OFF = XF_OFF   + NX   * 4;
static constexpr size_t LN1W_OFF = CLSF_OFF + NCLS * 4;
static constexpr size_t LN1B_OFF = LN1W_OFF + NLN1 * 4;
static constexpr size_t WQF_OFF  = LN1B_OFF + NLN1 * 4;   // Wq,Wk,Wv,Wo contiguous fp32
static constexpr size_t LN2W_OFF = WQF_OFF  + 4 * NWP * 4;
static constexpr size_t LN2B_OFF = LN2W_OFF + NLN2 * 4;
static constexpr size_t W1F_OFF  = LN2B_OFF + NLN2 * 4;
static constexpr size_t W2F_OFF  = W1F_OFF  + NW1  * 4;
static constexpr size_t X1H_OFF  = W2F_OFF  + NW1  * 4;   // frag-major planes
static constexpr size_t X1L_OFF  = X1H_OFF  + NX1F * 2;
static constexpr size_t QFH_OFF  = X1L_OFF  + NX1F * 2;
static constexpr size_t QFL_OFF  = QFH_OFF  + NQKF * 2;
static constexpr size_t KFH_OFF  = QFL_OFF  + NQKF * 2;
static constexpr size_t KFL_OFF  = KFH_OFF  + NQKF * 2;
static constexpr size_t VFH_OFF  = KFL_OFF  + NQKF * 2;
static constexpr size_t VFL_OFF  = VFH_OFF  + NVF  * 2;
static constexpr size_t ATH_OFF  = VFL_OFF  + NVF  * 2;
static constexpr size_t ATL_OFF  = ATH_OFF  + NX1F * 2;
static constexpr size_t XM_OFF   = ATL_OFF  + NX1F * 2;   // fp32 row-major
static constexpr size_t RES_OFF  = XM_OFF   + NRES * 4;   // fp32
static constexpr size_t X2N_OFF  = RES_OFF  + NRES * 4;   // fp32 (residual for FFN2)
static constexpr size_t X2NH_OFF = X2N_OFF  + NX2  * 4;
static constexpr size_t X2NL_OFF = X2NH_OFF + NX2F * 2;
static constexpr size_t HFH_OFF  = X2NL_OFF + NX2F * 2;
static constexpr size_t HFL_OFF  = HFH_OFF  + NHF  * 2;
static constexpr size_t WPH_OFF  = HFL_OFF  + NHF  * 2;   // 96 n-tiles x 12 kc (Wq..Wo)
static constexpr size_t WPL_OFF  = WPH_OFF  + 4 * NWP * 2;
static constexpr size_t WFH_OFF  = WPL_OFF  + 4 * NWP * 2; // W1 (96x12) then W2 (24x48)
static constexpr size_t WFL_OFF  = WFH_OFF  + 2 * NW1 * 2;
static constexpr size_t MU_OFF   = WFL_OFF  + 2 * NW1 * 2;
static constexpr size_t RS_OFF   = MU_OFF   + 128;
static constexpr size_t CID_OFF  = RS_OFF   + 128;
static constexpr size_t CAD_OFF  = CID_OFF  + NCLS * 8;
static constexpr size_t PERM_OFF = CAD_OFF  + (size_t)B_ * HW_ * 8;
static constexpr size_t FLAG_OFF = PERM_OFF + (size_t)B_ * (TP_ - 1) * 4;
static constexpr size_t PS_OFF   = FLAG_OFF + 16;
static constexpr size_t CIP_OFF  = PS_OFF + 32 * 16 * 16;
static constexpr size_t L2PS_OFF = CIP_OFF + (size_t)B_ * 8 * C_ * 8;
static constexpr size_t L2MU_OFF = L2PS_OFF + 32 * 8 * 16;
static constexpr size_t L2RS_OFF = L2MU_OFF + 128;
static constexpr size_t PART_OFF = L2RS_OFF + 128;        // FFN2 split-K partials
static constexpr size_t ARENA_BYTES = PART_OFF + 2 * NX2 * 4;

__device__ __align__(256) unsigned char g_arena[ARENA_BYTES];

template <typename Tp>
__device__ __forceinline__ Tp* ap(size_t off) { return (Tp*)(g_arena + off); }

// fp16 split with denormal protection: v = hi + lo/4096.
__device__ __forceinline__ void splitf(float v, f16& h, f16& l)
{
    float a = fabsf(v);
    f16 hv = (a >= 6.103515625e-05f) ? (f16)v : (f16)0.f;
    h = hv;
    l = (f16)((v - (float)hv) * 4096.f);
}

// A-frag-major element offset: row-tile / k-chunk / lane / elem
__device__ __forceinline__ size_t afrag(int row, int c, int KC)
{
    return ((size_t)((row >> 4) * KC + (c >> 5)) << 9)
         + (size_t)(((row & 15) | (((c >> 3) & 3) << 4)) << 3) + (c & 7);
}

// ---------------- dtype detect
__global__ void detect_kernel(const unsigned* __restrict__ w)
{
    if (threadIdx.x == 0)
        *ap<int>(FLAG_OFF) = (w[0] == 0x3F803F80u) ? 1 : 0;
}

// ---------------- single merged convert
struct SrcPtrs { const void* p[12]; };
static constexpr size_t SEGB[13] = {
    0,
    NX,
    NX + NCLS,
    NX + NCLS + NLN1,
    NX + NCLS + 2 * NLN1,
    NX + NCLS + 2 * NLN1 + NWP,
    NX + NCLS + 2 * NLN1 + 2 * NWP,
    NX + NCLS + 2 * NLN1 + 3 * NWP,
    NX + NCLS + 2 * NLN1 + 4 * NWP,
    NX + NCLS + 2 * NLN1 + 4 * NWP + NLN2,
    NX + NCLS + 2 * NLN1 + 4 * NWP + 2 * NLN2,
    NX + NCLS + 2 * NLN1 + 4 * NWP + 2 * NLN2 + NW1,
    NX + NCLS + 2 * NLN1 + 4 * NWP + 2 * NLN2 + 2 * NW1,
};
static constexpr size_t NTOT_CVT = SEGB[12];

__global__ __launch_bounds__(256) void cvt_all_kernel(SrcPtrs sp)
{
    size_t i = (size_t)blockIdx.x * 256 + threadIdx.x;
    if (i >= NTOT_CVT) return;
    int seg = 0;
#pragma unroll
    for (int k = 1; k < 12; k++) seg += (i >= SEGB[k]);
    size_t li = i - SEGB[seg];
    const void* src = sp.p[seg];
    float v = (*ap<int>(FLAG_OFF))
        ? __bfloat162float(((const bf16*)src)[li])
        : ((const float*)src)[li];
    ap<float>(XF_OFF)[i] = v;
}

// ---------------- weight repack: fp32 row-major -> frag-major f16 hi/lo
__global__ __launch_bounds__(256) void wrepack_kernel()
{
    size_t i = (size_t)blockIdx.x * 256 + threadIdx.x;
    const size_t n1 = 4 * NWP;
    if (i >= n1 + 2 * NW1) return;
    float v; f16 *oh, *ol;
    if (i < n1) {                     // stacked Wq,Wk,Wv,Wo: 96 n-tiles, KC=12
        size_t u = i;
        int blk = (int)(u >> 9), le = (int)(u & 511);
        int l = le >> 3, e = le & 7;
        int nt = blk / 12, kc = blk - nt * 12;
        int n = nt * 16 + (l & 15), k = kc * 32 + ((l >> 4) << 3) + e;
        v = ap<float>(WQF_OFF)[(size_t)n * C_ + k];
        oh = ap<f16>(WPH_OFF) + i; ol = ap<f16>(WPL_OFF) + i;
    } else if (i < n1 + NW1) {        // W1: 96 n-tiles, KC=12
        size_t u = i - n1;
        int blk = (int)(u >> 9), le = (int)(u & 511);
        int l = le >> 3, e = le & 7;
        int nt = blk / 12, kc = blk - nt * 12;
        int n = nt * 16 + (l & 15), k = kc * 32 + ((l >> 4) << 3) + e;
        v = ap<float>(W1F_OFF)[(size_t)n * C_ + k];
        oh = ap<f16>(WFH_OFF) + u; ol = ap<f16>(WFL_OFF) + u;
    } else {                          // W2: 24 n-tiles, KC=48
        size_t u = i - n1 - NW1;
        int blk = (int)(u >> 9), le = (int)(u & 511);
        int l = le >> 3, e = le & 7;
        int nt = blk / 48, kc = blk - nt * 48;
        int n = nt * 16 + (l & 15), k = kc * 32 + ((l >> 4) << 3) + e;
        v = ap<float>(W2F_OFF)[(size_t)n * FF_ + k];
        oh = ap<f16>(WFH_OFF) + NW1 + u; ol = ap<f16>(WFL_OFF) + NW1 + u;
    }
    f16 h, lo; splitf(v, h, lo);
    *oh = h; *ol = lo;
}

__device__ __forceinline__ float xin_val(int b, int t, int c)
{
    return (t == 0) ? ap<float>(CLSF_OFF)[b * C_ + c]
                    : ap<float>(XF_OFF)[((size_t)b * HW_ + (t - 1)) * C_ + c];
}

// ---------------- LN1 stats A/B, apply
__global__ __launch_bounds__(256) void stats1a_kernel()
{
    const int TC = T_ * C_;
    const int SL = (TC + 15) / 16;
    int b = blockIdx.x, s = blockIdx.y, tid = threadIdx.x;
    int e0 = s * SL, e1 = min(e0 + SL, TC);
    __shared__ double r1[256], r2[256];
    double sm = 0.0, s2 = 0.0;
    for (int e = e0 + tid; e < e1; e += 256) {
        int t = e / C_, c = e - t * C_;
        double v = (double)xin_val(b, t, c);
        sm += v; s2 += v * v;
    }
    r1[tid] = sm; r2[tid] = s2; __syncthreads();
    for (int o = 128; o; o >>= 1) {
        if (tid < o) { r1[tid] += r1[tid + o]; r2[tid] += r2[tid + o]; }
        __syncthreads();
    }
    if (tid == 0) {
        double2* ps = ap<double2>(PS_OFF);
        ps[b * 16 + s] = make_double2(r1[0], r2[0]);
    }
}

__global__ __launch_bounds__(64) void stats1b_kernel()
{
    int b = blockIdx.x, lane = threadIdx.x;
    const double2* ps = ap<double2>(PS_OFF);
    double sm = 0.0, s2 = 0.0;
    if (lane < 16) { sm = ps[b * 16 + lane].x; s2 = ps[b * 16 + lane].y; }
    for (int o = 8; o; o >>= 1) { sm += __shfl_down(sm, o); s2 += __shfl_down(s2, o); }
    if (lane == 0) {
        const int TC = T_ * C_;
        double m = sm / TC;
        double var = s2 / TC - m * m;
        ap<float>(MU_OFF)[b] = (float)m;
        ap<float>(RS_OFF)[b] = (float)(1.0 / sqrt(var + 1e-5));
    }
}

__global__ __launch_bounds__(256) void ln1_apply_kernel()
{
    size_t i = (size_t)blockIdx.x * 256 + threadIdx.x;
    if (i >= NRES) return;
    int grow = (int)(i / C_);
    int c = (int)(i - (size_t)grow * C_);
    int b = grow / T_, t = grow - b * T_;
    float v = xin_val(b, t, c);
    float r = (v - ap<float>(MU_OFF)[b]) * ap<float>(RS_OFF)[b]
              * ap<float>(LN1W_OFF)[t * C_ + c]
              + ap<float>(LN1B_OFF)[t * C_ + c];
    f16 h, l; splitf(r, h, l);
    size_t off = afrag(grow, c, 12);
    ap<f16>(X1H_OFF)[off] = h;
    ap<f16>(X1L_OFF)[off] = l;
}

// ---------------- direct-fragment split-fp16 MFMA GEMM (no LDS, no barriers)
// A frag-major [Mtiles][KC][512] hi/lo, B frag-major [Ntiles][KC][512] hi/lo.
// EMODE 2: gelu -> H frag; 4: XM fp32 + RES = v + x_in; 5: QKV frag routing
// (Q pre-scaled by 1/sqrt(d); V planes ordered [kc][dt]); 6: split-K(2) partials.
template<int EMODE>
__global__ __launch_bounds__(256, 2) void gemm_fd(
    size_t ah_off, size_t al_off, size_t bh_off, size_t bl_off,
    size_t c_off, int M, int N, int KC, int GY)
{
    // bijective XCD swizzle + y-major-within-x decomposition (A-panel L2 reuse)
    int nwg = (int)gridDim.x;
    int lin = blockIdx.x;
    int q8 = nwg >> 3, r8 = nwg & 7, xcd = lin & 7, pos = lin >> 3;
    int wg = (xcd < r8 ? xcd * (q8 + 1) : r8 * (q8 + 1) + (xcd - r8) * q8) + pos;
    int bx = wg / GY, by = wg - bx * GY;
    int kbeg = 0, kend = KC;
    if (EMODE == 6) { int ks = KC >> 1; kbeg = blockIdx.z * ks; kend = kbeg + ks; }
    int tid = threadIdx.x, w = tid >> 6, l = tid & 63;
    int wmt = bx * 8 + (w >> 1) * 4;
    int wnt = by * 8 + (w & 1) * 4;
    const f16* gAh = ap<f16>(ah_off);
    const f16* gAl = ap<f16>(al_off);
    const f16* gBh = ap<f16>(bh_off);
    const f16* gBl = ap<f16>(bl_off);
    size_t ab = (size_t)wmt * KC * 512 + (size_t)l * 8;
    size_t bb = (size_t)wnt * KC * 512 + (size_t)l * 8;

    const f32x4 zf = {0.f, 0.f, 0.f, 0.f};
    f32x4 acc1[4][4], acc2[4][4];
#pragma unroll
    for (int i = 0; i < 4; i++)
#pragma unroll
        for (int j = 0; j < 4; j++) { acc1[i][j] = zf; acc2[i][j] = zf; }

    for (int kc = kbeg; kc < kend; kc++) {
        f16x8 fah[4], fal[4], fbh[4], fbl[4];
#pragma unroll
        for (int i = 0; i < 4; i++) {
            size_t ao = ab + (size_t)(i * KC + kc) * 512;
            size_t bo = bb + (size_t)(i * KC + kc) * 512;
            fah[i] = *(const f16x8*)(gAh + ao);
            fal[i] = *(const f16x8*)(gAl + ao);
            fbh[i] = *(const f16x8*)(gBh + bo);
            fbl[i] = *(const f16x8*)(gBl + bo);
        }
        __builtin_amdgcn_s_setprio(1);
#pragma unroll
        for (int i = 0; i < 4; i++)
#pragma unroll
            for (int j = 0; j < 4; j++) {
                acc1[i][j] = MFMA16(fah[i], fbh[j], acc1[i][j]);
                acc2[i][j] = MFMA16(fah[i], fbl[j], acc2[i][j]);
                acc2[i][j] = MFMA16(fal[i], fbh[j], acc2[i][j]);
            }
        __builtin_amdgcn_s_setprio(0);
    }

    int l4 = ((l >> 4) << 2), lr = l & 15;
#pragma unroll
    for (int i = 0; i < 4; i++) {
        int rowb = (wmt + i) * 16 + l4;
#pragma unroll
        for (int j = 0; j < 4; j++) {
            int col = (wnt + j) * 16 + lr;
#pragma unroll
            for (int r = 0; r < 4; r++) {
                int row = rowb + r;
                if (row >= M) continue;
                float v = acc1[i][j][r] + acc2[i][j][r] * 0.000244140625f;
                if (EMODE == 5) {
                    int seg = col / C_;
                    int cn = col - seg * C_;
                    int hh = cn / D_, dd = cn - hh * D_;
                    int b2 = row / T_, t2 = row - b2 * T_;
                    int bh = b2 * H_ + hh;
                    float vv = (seg == 0) ? v * 0.14433756729740643f : v;
                    f16 h, lo; splitf(vv, h, lo);
                    if (seg < 2) {
                        size_t off = ((size_t)(bh * 112 + (t2 >> 4) * 2 + (dd >> 5)) << 9)
                                   + (size_t)(((t2 & 15) | (((dd >> 3) & 3) << 4)) << 3) + (dd & 7);
                        if (seg == 0) { ap<f16>(QFH_OFF)[off] = h; ap<f16>(QFL_OFF)[off] = lo; }
                        else          { ap<f16>(KFH_OFF)[off] = h; ap<f16>(KFL_OFF)[off] = lo; }
                    } else {
                        // V planes ordered [kc=t2>>5][dt=dd>>4] (window-contiguous)
                        size_t off = ((size_t)(bh * 75 + (t2 >> 5) * 3 + (dd >> 4)) << 9)
                                   + (size_t)(((dd & 15) | (((t2 >> 3) & 3) << 4)) << 3) + (t2 & 7);
                        ap<f16>(VFH_OFF)[off] = h; ap<f16>(VFL_OFF)[off] = lo;
                    }
                } else if (EMODE == 4) {
                    ap<float>(c_off)[(size_t)row * N + col] = v;
                    int b2 = row / T_, t2 = row - b2 * T_;
                    ap<float>(RES_OFF)[(size_t)row * N + col] = v + xin_val(b2, t2, col);
                } else if (EMODE == 2) {
                    float g = 0.5f * v * (1.f + erff(v * 0.70710678f));
                    f16 h, lo; splitf(g, h, lo);
                    size_t off = afrag(row, col, 48);
                    ap<f16>(HFH_OFF)[off] = h;
                    ap<f16>(HFL_OFF)[off] = lo;
                } else {  // 6
                    ap<float>(PART_OFF)[(size_t)blockIdx.z * NX2 + (size_t)row * N + col] = v;
                }
            }
        }
    }
}

// ---------------- fused flash attention, q-batch x2, bh-major XCD locality
// Pointer-increment addressing: K frag blocks are window-contiguous (+2048
// halfs/window, imm offsets 0/512/1024/1536); V planes [kc][dt] (+1536, imm
// 0/512/1024). s_setprio around both MFMA clusters. Exact defer-rescale.
// P-staging row stride = 40 halfs (80 B, multiple of 16 B -- b128 alignment).
__global__ __launch_bounds__(256) void flash_kernel()
{
    __shared__ f16 Plds[4][2][2][16][40];   // [wave][tile][plane][q][40]
    int nwg = (int)gridDim.x;               // 1792 = 256 bh * 7
    int lin = blockIdx.x;
    int q8 = nwg >> 3, r8 = nwg & 7, xcd = lin & 7, pos = lin >> 3;
    int wg = (xcd < r8 ? xcd * (q8 + 1) : r8 * (q8 + 1) + (xcd - r8) * q8) + pos;
    int bh = wg / 7, qblk = wg - bh * 7;
    int wv = threadIdx.x >> 6, l = threadIdx.x & 63;
    int qt0 = qblk * 8 + wv * 2;            // tiles qt0, qt0+1; 56 slots, 50 valid
    if (qt0 >= 50) return;
    int b = bh >> 3, h = bh & 7;
    size_t qkb = (size_t)bh * 57344;        // 56*2*512
    const f16* QH = ap<f16>(QFH_OFF) + qkb;
    const f16* QL = ap<f16>(QFL_OFF) + qkb;
    const f16* kptrH = ap<f16>(KFH_OFF) + qkb + (size_t)l * 8;
    const f16* kptrL = ap<f16>(KFL_OFF) + qkb + (size_t)l * 8;
    const f16* vptrH = ap<f16>(VFH_OFF) + (size_t)bh * 38400 + (size_t)l * 8;
    const f16* vptrL = ap<f16>(VFL_OFF) + (size_t)bh * 38400 + (size_t)l * 8;
    int myq = l & 15, g = l >> 4;

    f16x8 qh[2][2], ql[2][2];
#pragma unroll
    for (int u = 0; u < 2; u++)
#pragma unroll
        for (int kc = 0; kc < 2; kc++) {
            size_t qo = ((size_t)((qt0 + u) * 2 + kc) << 9) + (size_t)l * 8;
            qh[u][kc] = *(const f16x8*)(QH + qo);
            ql[u][kc] = *(const f16x8*)(QL + qo);
        }
    const f32x4 zf = {0.f, 0.f, 0.f, 0.f};
    f32x4 o1[2][3], o2[2][3];
#pragma unroll
    for (int u = 0; u < 2; u++)
#pragma unroll
        for (int j = 0; j < 3; j++) { o1[u][j] = zf; o2[u][j] = zf; }
    float mrun[2] = {-3e38f, -3e38f}, srun[2] = {0.f, 0.f};

    for (int w = 0; w < 25; w++) {
        // shared K and V fragment loads (imm-offset folded)
        f16x8 kh[4], kl[4];
#pragma unroll
        for (int t = 0; t < 4; t++) {
            kh[t] = *(const f16x8*)(kptrH + t * 512);
            kl[t] = *(const f16x8*)(kptrL + t * 512);
        }
        kptrH += 2048; kptrL += 2048;
        f16x8 vh[3], vl[3];
#pragma unroll
        for (int j = 0; j < 3; j++) {
            vh[j] = *(const f16x8*)(vptrH + j * 512);
            vl[j] = *(const f16x8*)(vptrL + j * 512);
        }
        vptrH += 1536; vptrL += 1536;
#pragma unroll
        for (int u = 0; u < 2; u++) {
            // S^T: lane holds S[key=(w*32+kt2*16+4g+r)][q=myq] (scale pre-folded in Q)
            f32x4 s1[2] = {zf, zf}, s2[2] = {zf, zf};
            __builtin_amdgcn_s_setprio(1);
#pragma unroll
            for (int kt2 = 0; kt2 < 2; kt2++)
#pragma unroll
                for (int kc = 0; kc < 2; kc++) {
                    int t = kt2 * 2 + kc;
                    s1[kt2] = MFMA16(kh[t], qh[u][kc], s1[kt2]);
                    s2[kt2] = MFMA16(kh[t], ql[u][kc], s2[kt2]);
                    s2[kt2] = MFMA16(kl[t], qh[u][kc], s2[kt2]);
                }
            __builtin_amdgcn_s_setprio(0);
            float sv[8];
#pragma unroll
            for (int kt2 = 0; kt2 < 2; kt2++)
#pragma unroll
                for (int r = 0; r < 4; r++)
                    sv[kt2 * 4 + r] = s1[kt2][r] + s2[kt2][r] * 0.000244140625f;
            if (w == 24) {                  // mask phantom keys 785..799
#pragma unroll
                for (int kt2 = 0; kt2 < 2; kt2++)
#pragma unroll
                    for (int r = 0; r < 4; r++)
                        if (kt2 * 16 + g * 4 + r >= 17) sv[kt2 * 4 + r] = -1e30f;
            }
            // per-q window max (tree + xor16/32 across the 4 g-groups)
            float pm = fmaxf(fmaxf(fmaxf(sv[0], sv[1]), fmaxf(sv[2], sv[3])),
                             fmaxf(fmaxf(sv[4], sv[5]), fmaxf(sv[6], sv[7])));
            pm = fmaxf(pm, __shfl_xor(pm, 16));
            pm = fmaxf(pm, __shfl_xor(pm, 32));
            float mnew = fmaxf(mrun[u], pm);
            float pv[8];
#pragma unroll
            for (int j2 = 0; j2 < 8; j2++) pv[j2] = __expf(sv[j2] - mnew);
            float ls = ((pv[0] + pv[1]) + (pv[2] + pv[3]))
                     + ((pv[4] + pv[5]) + (pv[6] + pv[7]));
            ls += __shfl_xor(ls, 16);
            ls += __shfl_xor(ls, 32);
            if (__any(pm > mrun[u])) {      // exact skip: fac==1 for all q otherwise
                float fac = __expf(mrun[u] - mnew);
                float fr[4];
#pragma unroll
                for (int r = 0; r < 4; r++) fr[r] = __shfl(fac, g * 4 + r);
#pragma unroll
                for (int j = 0; j < 3; j++)
#pragma unroll
                    for (int r = 0; r < 4; r++) { o1[u][j][r] *= fr[r]; o2[u][j][r] *= fr[r]; }
                srun[u] = srun[u] * fac + ls;
                mrun[u] = mnew;
            } else {
                srun[u] += ls;
            }
            // split P (pv >= 0: guard without fabs), stage through private LDS
#pragma unroll
            for (int kt2 = 0; kt2 < 2; kt2++) {
                f16x4 hh, llo;
#pragma unroll
                for (int r = 0; r < 4; r++) {
                    float pvv = pv[kt2 * 4 + r];
                    f16 a = (pvv >= 6.103515625e-05f) ? (f16)pvv : (f16)0.f;
                    hh[r] = a;
                    llo[r] = (f16)((pvv - (float)a) * 4096.f);
                }
                *(f16x4*)&Plds[wv][u][0][myq][kt2 * 16 + g * 4] = hh;
                *(f16x4*)&Plds[wv][u][1][myq][kt2 * 16 + g * 4] = llo;
            }
            f16x8 pah = *(const f16x8*)&Plds[wv][u][0][myq][g * 8];
            f16x8 pal = *(const f16x8*)&Plds[wv][u][1][myq][g * 8];
            // PV accumulate
            __builtin_amdgcn_s_setprio(1);
#pragma unroll
            for (int j = 0; j < 3; j++) {
                o1[u][j] = MFMA16(pah, vh[j], o1[u][j]);
                o2[u][j] = MFMA16(pah, vl[j], o2[u][j]);
                o2[u][j] = MFMA16(pal, vh[j], o2[u][j]);
            }
            __builtin_amdgcn_s_setprio(0);
        }
    }
    // epilogue: normalize, split-store to ATT frag planes
#pragma unroll
    for (int u = 0; u < 2; u++) {
        float inv = 1.f / srun[u];
        float ir[4];
#pragma unroll
        for (int r = 0; r < 4; r++) ir[r] = __shfl(inv, g * 4 + r);
#pragma unroll
        for (int j = 0; j < 3; j++) {
            int c = h * D_ + j * 16 + myq;   // col=lane&15=d
#pragma unroll
            for (int r = 0; r < 4; r++) {
                int q = (qt0 + u) * 16 + g * 4 + r;
                if (q >= T_) continue;
                float v = (o1[u][j][r] + o2[u][j][r] * 0.000244140625f) * ir[r];
                int grow = b * T_ + q;
                f16 hv, lv; splitf(v, hv, lv);
                size_t off = afrag(grow, c, 12);
                ap<f16>(ATH_OFF)[off] = hv;
                ap<f16>(ATL_OFF)[off] = lv;
            }
        }
    }
}

// ---------------- ci stage A/B (double)
__global__ __launch_bounds__(384) void cia_kernel()
{
    int b = blockIdx.x, s = blockIdx.y, c = threadIdx.x;
    const float* xm = ap<float>(XM_OFF);
    const int SL = (T_ + 7) / 8;
    int t0 = s * SL, t1 = min(t0 + SL, T_);
    double sm = 0.0;
    for (int t = t0; t < t1; t++) sm += (double)xm[((size_t)b * T_ + t) * C_ + c];
    ap<double>(CIP_OFF)[((size_t)b * 8 + s) * C_ + c] = sm;
}

__global__ __launch_bounds__(384) void cib_kernel()
{
    int b = blockIdx.x, c = threadIdx.x;
    const double* pp = ap<double>(CIP_OFF);
    double sm = 0.0;
#pragma unroll
    for (int s = 0; s < 8; s++) sm += pp[((size_t)b * 8 + s) * C_ + c];
    sm /= (double)T_;
    ap<double>(CID_OFF)[b * C_ + c] = 1.0 / (1.0 + exp(-sm));
}

// ---------------- ca (double), 4 rows per 256-thread block
__global__ __launch_bounds__(256) void ca_kernel()
{
    const float* xres1 = ap<float>(RES_OFF);
    const double* ci   = ap<double>(CID_OFF);
    int idx = blockIdx.x * 4 + (threadIdx.x >> 6);
    int b = idx / HW_, n = idx - b * HW_;
    int lane = threadIdx.x & 63;
    double s = 0.0;
    for (int c = lane; c < C_; c += 64)
        s += (double)xres1[((size_t)b * T_ + 1 + n) * C_ + c] * ci[b * C_ + c];
    for (int o = 32; o; o >>= 1) s += __shfl_down(s, o);
    if (lane == 0) ap<double>(CAD_OFF)[idx] = s;
}

// ---------------- stable rank
__global__ __launch_bounds__(256) void rank_kernel()
{
    const double* ca = ap<double>(CAD_OFF);
    int* perm = ap<int>(PERM_OFF);
    int b = blockIdx.x, tid = threadIdx.x;
    __shared__ double cs[HW_];
    for (int i = tid; i < HW_; i += 256) cs[i] = ca[b * HW_ + i];
    __syncthreads();
    for (int i = tid; i < HW_; i += 256) {
        double vi = cs[i];
        int r = 0;
        for (int j = 0; j < HW_; j++) {
            double vj = cs[j];
            r += (vj < vi) || (vj == vi && j < i);
        }
        if (r >= HW_ - TP_ + 1) perm[b * (TP_ - 1) + (r - (HW_ - TP_ + 1))] = i;
    }
}

// ---------------- LN2 A/B/apply
__global__ __launch_bounds__(256) void ln2a_kernel()
{
    const float* xres1 = ap<float>(RES_OFF);
    const int* perm = ap<int>(PERM_OFF);
    const int TC = TP_ * C_;
    const int SL = (TC + 7) / 8;
    int b = blockIdx.x, s = blockIdx.y, tid = threadIdx.x;
    int e0 = s * SL, e1 = min(e0 + SL, TC);
    __shared__ double r1[256], r2[256];
    double sm = 0.0, s2 = 0.0;
    for (int e = e0 + tid; e < e1; e += 256) {
        int t = e / C_, c = e - t * C_;
        int st = (t == 0) ? 0 : 1 + perm[b * (TP_ - 1) + t - 1];
        double v = (double)xres1[((size_t)b * T_ + st) * C_ + c];
        sm += v; s2 += v * v;
    }
    r1[tid] = sm; r2[tid] = s2; __syncthreads();
    for (int o = 128; o; o >>= 1) {
        if (tid < o) { r1[tid] += r1[tid + o]; r2[tid] += r2[tid + o]; }
        __syncthreads();
    }
    if (tid == 0) {
        double2* ps = ap<double2>(L2PS_OFF);
        ps[b * 8 + s] = make_double2(r1[0], r2[0]);
    }
}

__global__ __launch_bounds__(64) void ln2b_kernel()
{
    int b = blockIdx.x, lane = threadIdx.x;
    const double2* ps = ap<double2>(L2PS_OFF);
    double sm = 0.0, s2 = 0.0;
    if (lane < 8) { sm = ps[b * 8 + lane].x; s2 = ps[b * 8 + lane].y; }
    for (int o = 4; o; o >>= 1) { sm += __shfl_down(sm, o); s2 += __shfl_down(s2, o); }
    if (lane == 0) {
        const int TC = TP_ * C_;
        double m = sm / TC;
        double var = s2 / TC - m * m;
        ap<float>(L2MU_OFF)[b] = (float)m;
        ap<float>(L2RS_OFF)[b] = (float)(1.0 / sqrt(var + 1e-5));
    }
}

__global__ __launch_bounds__(256) void ln2_apply_kernel()
{
    size_t i = (size_t)blockIdx.x * 256 + threadIdx.x;
    if (i >= NX2) return;
    const int TC = TP_ * C_;
    int b = (int)(i / TC);
    int e = (int)(i - (size_t)b * TC);
    int t = e / C_, c = e - t * C_;
    const int* perm = ap<int>(PERM_OFF);
    int st = (t == 0) ? 0 : 1 + perm[b * (TP_ - 1) + t - 1];
    float v = ap<float>(RES_OFF)[((size_t)b * T_ + st) * C_ + c];
    float r = (v - ap<float>(L2MU_OFF)[b]) * ap<float>(L2RS_OFF)[b]
              * ap<float>(LN2W_OFF)[e] + ap<float>(LN2B_OFF)[e];
    ap<float>(X2N_OFF)[i] = r;
    int grow = b * TP_ + t;
    f16 h, l; splitf(r, h, l);
    size_t off = afrag(grow, c, 12);
    ap<f16>(X2NH_OFF)[off] = h;
    ap<f16>(X2NL_OFF)[off] = l;
}

// ---------------- FFN2 reduce: 2 split-K partials + x2n resid -> split store
__global__ __launch_bounds__(256) void ffn2_reduce_kernel(float* __restrict__ out)
{
    const size_t tot = NX2;
    size_t i = (size_t)blockIdx.x * 256 + threadIdx.x;
    if (i >= tot) return;
    const float* part = ap<float>(PART_OFF);
    float v = part[i] + part[tot + i] + ap<float>(X2N_OFF)[i];
    int gm = (int)(i / C_);
    int gn = (int)(i - (size_t)gm * C_);
    int b = gm / TP_, t = gm - b * TP_;
    size_t off = (t == 0)
        ? ((size_t)B_ * (TP_ - 1) * C_ + (size_t)b * C_ + gn)
        : ((size_t)(b * (TP_ - 1) + (t - 1)) * C_ + gn);
    out[off] = v;
}

extern "C" void kernel_launch(void* const* d_in, const int* in_sizes, int n_in,
                              void* d_out, int out_size, void* d_ws, size_t ws_size,
                              hipStream_t stream)
{
    float* out = (float*)d_out;
    (void)d_ws; (void)ws_size; (void)in_sizes; (void)n_in; (void)out_size;

    const int M1 = B_ * T_;            // 25120
    const int M2 = B_ * TP_;           // 6304

    // 0. dtype detect + merged conversion + weight frag repack
    detect_kernel<<<1, 64, 0, stream>>>((const unsigned*)d_in[2]);
    SrcPtrs sp;
    for (int i = 0; i < 12; i++) sp.p[i] = d_in[i];
    cvt_all_kernel<<<(int)((NTOT_CVT + 255) / 256), 256, 0, stream>>>(sp);
    wrepack_kernel<<<(int)((4 * NWP + 2 * NW1 + 255) / 256), 256, 0, stream>>>();

    // 1. LN1 (emits X1 frag planes)
    stats1a_kernel<<<dim3(B_, 16), 256, 0, stream>>>();
    stats1b_kernel<<<B_, 64, 0, stream>>>();
    ln1_apply_kernel<<<(int)((NRES + 255) / 256), 256, 0, stream>>>();

    // 2. merged QKV projection (direct-frag MFMA -> Q/K/V frag planes)
    gemm_fd<5><<<dim3(197 * 9), 256, 0, stream>>>(
        X1H_OFF, X1L_OFF, WPH_OFF, WPL_OFF, 0, M1, 3 * C_, 12, 9);

    // 3. fused flash attention (q-batch x2, bh-major XCD-local grid)
    flash_kernel<<<dim3(256 * 7), 256, 0, stream>>>();

    // Wo projection fused with residual (B = tiles 72..95 of WQKVO frag pack)
    gemm_fd<4><<<dim3(197 * 3), 256, 0, stream>>>(
        ATH_OFF, ATL_OFF,
        WPH_OFF + (size_t)442368 * 2, WPL_OFF + (size_t)442368 * 2,
        XM_OFF, M1, C_, 12, 3);

    // 4. ci, ca, rank, LN2 (fp32/fp64 ordering path unchanged)
    cia_kernel<<<dim3(B_, 8), 384, 0, stream>>>();
    cib_kernel<<<B_, 384, 0, stream>>>();
    ca_kernel<<<B_ * HW_ / 4, 256, 0, stream>>>();
    rank_kernel<<<B_, 256, 0, stream>>>();
    ln2a_kernel<<<dim3(B_, 8), 256, 0, stream>>>();
    ln2b_kernel<<<B_, 64, 0, stream>>>();
    ln2_apply_kernel<<<(int)((NX2 + 255) / 256), 256, 0, stream>>>();

    // 5. FFN: gelu GEMM -> H frag, split-K=2 GEMM + reduce
    gemm_fd<2><<<dim3(50 * 12), 256, 0, stream>>>(
        X2NH_OFF, X2NL_OFF, WFH_OFF, WFL_OFF, 0, M2, FF_, 12, 12);
    gemm_fd<6><<<dim3(50 * 3, 1, 2), 256, 0, stream>>>(
        HFH_OFF, HFL_OFF, WFH_OFF + NW1 * 2, WFL_OFF + NW1 * 2, 0, M2, C_, 48, 3);
    ffn2_reduce_kernel<<<(int)((NX2 + 255) / 256), 256, 0, stream>>>(out);
}

// Round 8
// 895.074 us; speedup vs baseline: 1.1981x; 1.1981x over previous
//
#include <hip/hip_runtime.h>
#include <hip/hip_bf16.h>
#include <math.h>

typedef __hip_bfloat16 bf16;
typedef _Float16 f16;
typedef __attribute__((ext_vector_type(8))) _Float16 f16x8;
typedef __attribute__((ext_vector_type(4))) _Float16 f16x4;
typedef __attribute__((ext_vector_type(4))) float f32x4;

#define B_ 32
#define HW_ 784
#define T_ 785
#define TP_ 197
#define C_ 384
#define H_ 8
#define D_ 48
#define FF_ 1536

#define MFMA16(a, b, c) __builtin_amdgcn_mfma_f32_16x16x32_f16(a, b, c, 0, 0, 0)

// ---------------- sizes (elements) ----------------
static constexpr size_t NRES = (size_t)B_ * T_ * C_;
static constexpr size_t NX   = (size_t)B_ * HW_ * C_;
static constexpr size_t NCLS = (size_t)B_ * C_;
static constexpr size_t NLN1 = (size_t)T_ * C_;
static constexpr size_t NWP  = (size_t)C_ * C_;
static constexpr size_t NLN2 = (size_t)TP_ * C_;
static constexpr size_t NW1  = (size_t)FF_ * C_;
static constexpr size_t NX2  = (size_t)B_ * TP_ * C_;
static constexpr size_t NH   = (size_t)B_ * TP_ * FF_;

// frag-major plane sizes (halfs)
static constexpr size_t NX1F = (size_t)1576 * 12 * 512;   // M1 rows padded to 25216
static constexpr size_t NQKF = (size_t)256 * 56 * 2 * 512; // per-bh 56 t-tiles x 2 kc
static constexpr size_t NVF  = (size_t)256 * 3 * 25 * 512; // per-bh 25 kc x 3 d-tiles
static constexpr size_t NX2F = (size_t)400 * 12 * 512;     // M2 rows padded to 6400
static constexpr size_t NHF  = (size_t)400 * 48 * 512;

// ---------------- arena byte offsets ----------------
static constexpr size_t XF_OFF   = 0;
static constexpr size_t CLSF_OFF = XF_OFF   + NX   * 4;
static constexpr size_t LN1W_OFF = CLSF_OFF + NCLS * 4;
static constexpr size_t LN1B_OFF = LN1W_OFF + NLN1 * 4;
static constexpr size_t WQF_OFF  = LN1B_OFF + NLN1 * 4;   // Wq,Wk,Wv,Wo contiguous fp32
static constexpr size_t LN2W_OFF = WQF_OFF  + 4 * NWP * 4;
static constexpr size_t LN2B_OFF = LN2W_OFF + NLN2 * 4;
static constexpr size_t W1F_OFF  = LN2B_OFF + NLN2 * 4;
static constexpr size_t W2F_OFF  = W1F_OFF  + NW1  * 4;
static constexpr size_t X1H_OFF  = W2F_OFF  + NW1  * 4;   // frag-major planes
static constexpr size_t X1L_OFF  = X1H_OFF  + NX1F * 2;
static constexpr size_t QFH_OFF  = X1L_OFF  + NX1F * 2;
static constexpr size_t QFL_OFF  = QFH_OFF  + NQKF * 2;
static constexpr size_t KFH_OFF  = QFL_OFF  + NQKF * 2;
static constexpr size_t KFL_OFF  = KFH_OFF  + NQKF * 2;
static constexpr size_t VFH_OFF  = KFL_OFF  + NQKF * 2;
static constexpr size_t VFL_OFF  = VFH_OFF  + NVF  * 2;
static constexpr size_t ATH_OFF  = VFL_OFF  + NVF  * 2;
static constexpr size_t ATL_OFF  = ATH_OFF  + NX1F * 2;
static constexpr size_t XM_OFF   = ATL_OFF  + NX1F * 2;   // fp32 row-major
static constexpr size_t RES_OFF  = XM_OFF   + NRES * 4;   // fp32
static constexpr size_t X2N_OFF  = RES_OFF  + NRES * 4;   // fp32 (residual for FFN2)
static constexpr size_t X2NH_OFF = X2N_OFF  + NX2  * 4;
static constexpr size_t X2NL_OFF = X2NH_OFF + NX2F * 2;
static constexpr size_t HFH_OFF  = X2NL_OFF + NX2F * 2;
static constexpr size_t HFL_OFF  = HFH_OFF  + NHF  * 2;
static constexpr size_t WPH_OFF  = HFL_OFF  + NHF  * 2;   // 96 n-tiles x 12 kc (Wq..Wo)
static constexpr size_t WPL_OFF  = WPH_OFF  + 4 * NWP * 2;
static constexpr size_t WFH_OFF  = WPL_OFF  + 4 * NWP * 2; // W1 (96x12) then W2 (24x48)
static constexpr size_t WFL_OFF  = WFH_OFF  + 2 * NW1 * 2;
static constexpr size_t MU_OFF   = WFL_OFF  + 2 * NW1 * 2;
static constexpr size_t RS_OFF   = MU_OFF   + 128;
static constexpr size_t CID_OFF  = RS_OFF   + 128;
static constexpr size_t CAD_OFF  = CID_OFF  + NCLS * 8;
static constexpr size_t PERM_OFF = CAD_OFF  + (size_t)B_ * HW_ * 8;
static constexpr size_t FLAG_OFF = PERM_OFF + (size_t)B_ * (TP_ - 1) * 4;
static constexpr size_t PS_OFF   = FLAG_OFF + 16;
static constexpr size_t CIP_OFF  = PS_OFF + 32 * 16 * 16;
static constexpr size_t L2PS_OFF = CIP_OFF + (size_t)B_ * 8 * C_ * 8;
static constexpr size_t L2MU_OFF = L2PS_OFF + 32 * 8 * 16;
static constexpr size_t L2RS_OFF = L2MU_OFF + 128;
static constexpr size_t PART_OFF = L2RS_OFF + 128;        // FFN2 split-K partials
static constexpr size_t ARENA_BYTES = PART_OFF + 2 * NX2 * 4;

__device__ __align__(256) unsigned char g_arena[ARENA_BYTES];

template <typename Tp>
__device__ __forceinline__ Tp* ap(size_t off) { return (Tp*)(g_arena + off); }

// fp16 split with denormal protection: v = hi + lo/4096.
__device__ __forceinline__ void splitf(float v, f16& h, f16& l)
{
    float a = fabsf(v);
    f16 hv = (a >= 6.103515625e-05f) ? (f16)v : (f16)0.f;
    h = hv;
    l = (f16)((v - (float)hv) * 4096.f);
}

// A-frag-major element offset: row-tile / k-chunk / lane / elem
__device__ __forceinline__ size_t afrag(int row, int c, int KC)
{
    return ((size_t)((row >> 4) * KC + (c >> 5)) << 9)
         + (size_t)(((row & 15) | (((c >> 3) & 3) << 4)) << 3) + (c & 7);
}

// ---------------- dtype detect
__global__ void detect_kernel(const unsigned* __restrict__ w)
{
    if (threadIdx.x == 0)
        *ap<int>(FLAG_OFF) = (w[0] == 0x3F803F80u) ? 1 : 0;
}

// ---------------- single merged convert
struct SrcPtrs { const void* p[12]; };
static constexpr size_t SEGB[13] = {
    0,
    NX,
    NX + NCLS,
    NX + NCLS + NLN1,
    NX + NCLS + 2 * NLN1,
    NX + NCLS + 2 * NLN1 + NWP,
    NX + NCLS + 2 * NLN1 + 2 * NWP,
    NX + NCLS + 2 * NLN1 + 3 * NWP,
    NX + NCLS + 2 * NLN1 + 4 * NWP,
    NX + NCLS + 2 * NLN1 + 4 * NWP + NLN2,
    NX + NCLS + 2 * NLN1 + 4 * NWP + 2 * NLN2,
    NX + NCLS + 2 * NLN1 + 4 * NWP + 2 * NLN2 + NW1,
    NX + NCLS + 2 * NLN1 + 4 * NWP + 2 * NLN2 + 2 * NW1,
};
static constexpr size_t NTOT_CVT = SEGB[12];

__global__ __launch_bounds__(256) void cvt_all_kernel(SrcPtrs sp)
{
    size_t i = (size_t)blockIdx.x * 256 + threadIdx.x;
    if (i >= NTOT_CVT) return;
    int seg = 0;
#pragma unroll
    for (int k = 1; k < 12; k++) seg += (i >= SEGB[k]);
    size_t li = i - SEGB[seg];
    const void* src = sp.p[seg];
    float v = (*ap<int>(FLAG_OFF))
        ? __bfloat162float(((const bf16*)src)[li])
        : ((const float*)src)[li];
    ap<float>(XF_OFF)[i] = v;
}

// ---------------- weight repack: fp32 row-major -> frag-major f16 hi/lo
__global__ __launch_bounds__(256) void wrepack_kernel()
{
    size_t i = (size_t)blockIdx.x * 256 + threadIdx.x;
    const size_t n1 = 4 * NWP;
    if (i >= n1 + 2 * NW1) return;
    float v; f16 *oh, *ol;
    if (i < n1) {                     // stacked Wq,Wk,Wv,Wo: 96 n-tiles, KC=12
        size_t u = i;
        int blk = (int)(u >> 9), le = (int)(u & 511);
        int l = le >> 3, e = le & 7;
        int nt = blk / 12, kc = blk - nt * 12;
        int n = nt * 16 + (l & 15), k = kc * 32 + ((l >> 4) << 3) + e;
        v = ap<float>(WQF_OFF)[(size_t)n * C_ + k];
        oh = ap<f16>(WPH_OFF) + i; ol = ap<f16>(WPL_OFF) + i;
    } else if (i < n1 + NW1) {        // W1: 96 n-tiles, KC=12
        size_t u = i - n1;
        int blk = (int)(u >> 9), le = (int)(u & 511);
        int l = le >> 3, e = le & 7;
        int nt = blk / 12, kc = blk - nt * 12;
        int n = nt * 16 + (l & 15), k = kc * 32 + ((l >> 4) << 3) + e;
        v = ap<float>(W1F_OFF)[(size_t)n * C_ + k];
        oh = ap<f16>(WFH_OFF) + u; ol = ap<f16>(WFL_OFF) + u;
    } else {                          // W2: 24 n-tiles, KC=48
        size_t u = i - n1 - NW1;
        int blk = (int)(u >> 9), le = (int)(u & 511);
        int l = le >> 3, e = le & 7;
        int nt = blk / 48, kc = blk - nt * 48;
        int n = nt * 16 + (l & 15), k = kc * 32 + ((l >> 4) << 3) + e;
        v = ap<float>(W2F_OFF)[(size_t)n * FF_ + k];
        oh = ap<f16>(WFH_OFF) + NW1 + u; ol = ap<f16>(WFL_OFF) + NW1 + u;
    }
    f16 h, lo; splitf(v, h, lo);
    *oh = h; *ol = lo;
}

__device__ __forceinline__ float xin_val(int b, int t, int c)
{
    return (t == 0) ? ap<float>(CLSF_OFF)[b * C_ + c]
                    : ap<float>(XF_OFF)[((size_t)b * HW_ + (t - 1)) * C_ + c];
}

// ---------------- LN1 stats A/B, apply
__global__ __launch_bounds__(256) void stats1a_kernel()
{
    const int TC = T_ * C_;
    const int SL = (TC + 15) / 16;
    int b = blockIdx.x, s = blockIdx.y, tid = threadIdx.x;
    int e0 = s * SL, e1 = min(e0 + SL, TC);
    __shared__ double r1[256], r2[256];
    double sm = 0.0, s2 = 0.0;
    for (int e = e0 + tid; e < e1; e += 256) {
        int t = e / C_, c = e - t * C_;
        double v = (double)xin_val(b, t, c);
        sm += v; s2 += v * v;
    }
    r1[tid] = sm; r2[tid] = s2; __syncthreads();
    for (int o = 128; o; o >>= 1) {
        if (tid < o) { r1[tid] += r1[tid + o]; r2[tid] += r2[tid + o]; }
        __syncthreads();
    }
    if (tid == 0) {
        double2* ps = ap<double2>(PS_OFF);
        ps[b * 16 + s] = make_double2(r1[0], r2[0]);
    }
}

__global__ __launch_bounds__(64) void stats1b_kernel()
{
    int b = blockIdx.x, lane = threadIdx.x;
    const double2* ps = ap<double2>(PS_OFF);
    double sm = 0.0, s2 = 0.0;
    if (lane < 16) { sm = ps[b * 16 + lane].x; s2 = ps[b * 16 + lane].y; }
    for (int o = 8; o; o >>= 1) { sm += __shfl_down(sm, o); s2 += __shfl_down(s2, o); }
    if (lane == 0) {
        const int TC = T_ * C_;
        double m = sm / TC;
        double var = s2 / TC - m * m;
        ap<float>(MU_OFF)[b] = (float)m;
        ap<float>(RS_OFF)[b] = (float)(1.0 / sqrt(var + 1e-5));
    }
}

__global__ __launch_bounds__(256) void ln1_apply_kernel()
{
    size_t i = (size_t)blockIdx.x * 256 + threadIdx.x;
    if (i >= NRES) return;
    int grow = (int)(i / C_);
    int c = (int)(i - (size_t)grow * C_);
    int b = grow / T_, t = grow - b * T_;
    float v = xin_val(b, t, c);
    float r = (v - ap<float>(MU_OFF)[b]) * ap<float>(RS_OFF)[b]
              * ap<float>(LN1W_OFF)[t * C_ + c]
              + ap<float>(LN1B_OFF)[t * C_ + c];
    f16 h, l; splitf(r, h, l);
    size_t off = afrag(grow, c, 12);
    ap<f16>(X1H_OFF)[off] = h;
    ap<f16>(X1L_OFF)[off] = l;
}

// ---------------- direct-fragment split-fp16 MFMA GEMM (no LDS, no barriers)
// A frag-major [Mtiles][KC][512] hi/lo, B frag-major [Ntiles][KC][512] hi/lo.
// EMODE 2: gelu -> H frag; 4: XM fp32 + RES = v + x_in; 5: QKV frag routing
// (Q pre-scaled by 1/sqrt(d); V planes ordered [kc][dt]); 6: split-K(2) partials.
template<int EMODE>
__global__ __launch_bounds__(256, 2) void gemm_fd(
    size_t ah_off, size_t al_off, size_t bh_off, size_t bl_off,
    size_t c_off, int M, int N, int KC, int GY)
{
    // bijective XCD swizzle + y-major-within-x decomposition (A-panel L2 reuse)
    int nwg = (int)gridDim.x;
    int lin = blockIdx.x;
    int q8 = nwg >> 3, r8 = nwg & 7, xcd = lin & 7, pos = lin >> 3;
    int wg = (xcd < r8 ? xcd * (q8 + 1) : r8 * (q8 + 1) + (xcd - r8) * q8) + pos;
    int bx = wg / GY, by = wg - bx * GY;
    int kbeg = 0, kend = KC;
    if (EMODE == 6) { int ks = KC >> 1; kbeg = blockIdx.z * ks; kend = kbeg + ks; }
    int tid = threadIdx.x, w = tid >> 6, l = tid & 63;
    int wmt = bx * 8 + (w >> 1) * 4;
    int wnt = by * 8 + (w & 1) * 4;
    const f16* gAh = ap<f16>(ah_off);
    const f16* gAl = ap<f16>(al_off);
    const f16* gBh = ap<f16>(bh_off);
    const f16* gBl = ap<f16>(bl_off);
    size_t ab = (size_t)wmt * KC * 512 + (size_t)l * 8;
    size_t bb = (size_t)wnt * KC * 512 + (size_t)l * 8;

    const f32x4 zf = {0.f, 0.f, 0.f, 0.f};
    f32x4 acc1[4][4], acc2[4][4];
#pragma unroll
    for (int i = 0; i < 4; i++)
#pragma unroll
        for (int j = 0; j < 4; j++) { acc1[i][j] = zf; acc2[i][j] = zf; }

    for (int kc = kbeg; kc < kend; kc++) {
        f16x8 fah[4], fal[4], fbh[4], fbl[4];
#pragma unroll
        for (int i = 0; i < 4; i++) {
            size_t ao = ab + (size_t)(i * KC + kc) * 512;
            size_t bo = bb + (size_t)(i * KC + kc) * 512;
            fah[i] = *(const f16x8*)(gAh + ao);
            fal[i] = *(const f16x8*)(gAl + ao);
            fbh[i] = *(const f16x8*)(gBh + bo);
            fbl[i] = *(const f16x8*)(gBl + bo);
        }
        __builtin_amdgcn_s_setprio(1);
#pragma unroll
        for (int i = 0; i < 4; i++)
#pragma unroll
            for (int j = 0; j < 4; j++) {
                acc1[i][j] = MFMA16(fah[i], fbh[j], acc1[i][j]);
                acc2[i][j] = MFMA16(fah[i], fbl[j], acc2[i][j]);
                acc2[i][j] = MFMA16(fal[i], fbh[j], acc2[i][j]);
            }
        __builtin_amdgcn_s_setprio(0);
    }

    int l4 = ((l >> 4) << 2), lr = l & 15;
#pragma unroll
    for (int i = 0; i < 4; i++) {
        int rowb = (wmt + i) * 16 + l4;
#pragma unroll
        for (int j = 0; j < 4; j++) {
            int col = (wnt + j) * 16 + lr;
#pragma unroll
            for (int r = 0; r < 4; r++) {
                int row = rowb + r;
                if (row >= M) continue;
                float v = acc1[i][j][r] + acc2[i][j][r] * 0.000244140625f;
                if (EMODE == 5) {
                    int seg = col / C_;
                    int cn = col - seg * C_;
                    int hh = cn / D_, dd = cn - hh * D_;
                    int b2 = row / T_, t2 = row - b2 * T_;
                    int bh = b2 * H_ + hh;
                    float vv = (seg == 0) ? v * 0.14433756729740643f : v;
                    f16 h, lo; splitf(vv, h, lo);
                    if (seg < 2) {
                        size_t off = ((size_t)(bh * 112 + (t2 >> 4) * 2 + (dd >> 5)) << 9)
                                   + (size_t)(((t2 & 15) | (((dd >> 3) & 3) << 4)) << 3) + (dd & 7);
                        if (seg == 0) { ap<f16>(QFH_OFF)[off] = h; ap<f16>(QFL_OFF)[off] = lo; }
                        else          { ap<f16>(KFH_OFF)[off] = h; ap<f16>(KFL_OFF)[off] = lo; }
                    } else {
                        // V planes ordered [kc=t2>>5][dt=dd>>4] (window-contiguous)
                        size_t off = ((size_t)(bh * 75 + (t2 >> 5) * 3 + (dd >> 4)) << 9)
                                   + (size_t)(((dd & 15) | (((t2 >> 3) & 3) << 4)) << 3) + (t2 & 7);
                        ap<f16>(VFH_OFF)[off] = h; ap<f16>(VFL_OFF)[off] = lo;
                    }
                } else if (EMODE == 4) {
                    ap<float>(c_off)[(size_t)row * N + col] = v;
                    int b2 = row / T_, t2 = row - b2 * T_;
                    ap<float>(RES_OFF)[(size_t)row * N + col] = v + xin_val(b2, t2, col);
                } else if (EMODE == 2) {
                    float g = 0.5f * v * (1.f + erff(v * 0.70710678f));
                    f16 h, lo; splitf(g, h, lo);
                    size_t off = afrag(row, col, 48);
                    ap<f16>(HFH_OFF)[off] = h;
                    ap<f16>(HFL_OFF)[off] = lo;
                } else {  // 6
                    ap<float>(PART_OFF)[(size_t)blockIdx.z * NX2 + (size_t)row * N + col] = v;
                }
            }
        }
    }
}

// ---------------- fused flash attention, q-batch x2, bh-major XCD locality
// Pointer-increment addressing (K +2048/window, V [kc][dt] +1536/window).
// NO setprio here: this kernel is VALU-bound (softmax+split); prioritizing
// MFMA-phase waves starves the bottleneck pipe (round-7 post-mortem:
// VALUBusy 57->50, dur +12%). Exact defer-rescale. P-staging row stride =
// 40 halfs (80 B, multiple of 16 B -- b128 alignment requirement).
__global__ __launch_bounds__(256) void flash_kernel()
{
    __shared__ f16 Plds[4][2][2][16][40];   // [wave][tile][plane][q][40]
    int nwg = (int)gridDim.x;               // 1792 = 256 bh * 7
    int lin = blockIdx.x;
    int q8 = nwg >> 3, r8 = nwg & 7, xcd = lin & 7, pos = lin >> 3;
    int wg = (xcd < r8 ? xcd * (q8 + 1) : r8 * (q8 + 1) + (xcd - r8) * q8) + pos;
    int bh = wg / 7, qblk = wg - bh * 7;
    int wv = threadIdx.x >> 6, l = threadIdx.x & 63;
    int qt0 = qblk * 8 + wv * 2;            // tiles qt0, qt0+1; 56 slots, 50 valid
    if (qt0 >= 50) return;
    int b = bh >> 3, h = bh & 7;
    size_t qkb = (size_t)bh * 57344;        // 56*2*512
    const f16* QH = ap<f16>(QFH_OFF) + qkb;
    const f16* QL = ap<f16>(QFL_OFF) + qkb;
    const f16* kptrH = ap<f16>(KFH_OFF) + qkb + (size_t)l * 8;
    const f16* kptrL = ap<f16>(KFL_OFF) + qkb + (size_t)l * 8;
    const f16* vptrH = ap<f16>(VFH_OFF) + (size_t)bh * 38400 + (size_t)l * 8;
    const f16* vptrL = ap<f16>(VFL_OFF) + (size_t)bh * 38400 + (size_t)l * 8;
    int myq = l & 15, g = l >> 4;

    f16x8 qh[2][2], ql[2][2];
#pragma unroll
    for (int u = 0; u < 2; u++)
#pragma unroll
        for (int kc = 0; kc < 2; kc++) {
            size_t qo = ((size_t)((qt0 + u) * 2 + kc) << 9) + (size_t)l * 8;
            qh[u][kc] = *(const f16x8*)(QH + qo);
            ql[u][kc] = *(const f16x8*)(QL + qo);
        }
    const f32x4 zf = {0.f, 0.f, 0.f, 0.f};
    f32x4 o1[2][3], o2[2][3];
#pragma unroll
    for (int u = 0; u < 2; u++)
#pragma unroll
        for (int j = 0; j < 3; j++) { o1[u][j] = zf; o2[u][j] = zf; }
    float mrun[2] = {-3e38f, -3e38f}, srun[2] = {0.f, 0.f};

    for (int w = 0; w < 25; w++) {
        // shared K and V fragment loads (imm-offset folded)
        f16x8 kh[4], kl[4];
#pragma unroll
        for (int t = 0; t < 4; t++) {
            kh[t] = *(const f16x8*)(kptrH + t * 512);
            kl[t] = *(const f16x8*)(kptrL + t * 512);
        }
        kptrH += 2048; kptrL += 2048;
        f16x8 vh[3], vl[3];
#pragma unroll
        for (int j = 0; j < 3; j++) {
            vh[j] = *(const f16x8*)(vptrH + j * 512);
            vl[j] = *(const f16x8*)(vptrL + j * 512);
        }
        vptrH += 1536; vptrL += 1536;
#pragma unroll
        for (int u = 0; u < 2; u++) {
            // S^T: lane holds S[key=(w*32+kt2*16+4g+r)][q=myq] (scale pre-folded in Q)
            f32x4 s1[2] = {zf, zf}, s2[2] = {zf, zf};
#pragma unroll
            for (int kt2 = 0; kt2 < 2; kt2++)
#pragma unroll
                for (int kc = 0; kc < 2; kc++) {
                    int t = kt2 * 2 + kc;
                    s1[kt2] = MFMA16(kh[t], qh[u][kc], s1[kt2]);
                    s2[kt2] = MFMA16(kh[t], ql[u][kc], s2[kt2]);
                    s2[kt2] = MFMA16(kl[t], qh[u][kc], s2[kt2]);
                }
            float sv[8];
#pragma unroll
            for (int kt2 = 0; kt2 < 2; kt2++)
#pragma unroll
                for (int r = 0; r < 4; r++)
                    sv[kt2 * 4 + r] = s1[kt2][r] + s2[kt2][r] * 0.000244140625f;
            if (w == 24) {                  // mask phantom keys 785..799
#pragma unroll
                for (int kt2 = 0; kt2 < 2; kt2++)
#pragma unroll
                    for (int r = 0; r < 4; r++)
                        if (kt2 * 16 + g * 4 + r >= 17) sv[kt2 * 4 + r] = -1e30f;
            }
            // per-q window max (tree + xor16/32 across the 4 g-groups)
            float pm = fmaxf(fmaxf(fmaxf(sv[0], sv[1]), fmaxf(sv[2], sv[3])),
                             fmaxf(fmaxf(sv[4], sv[5]), fmaxf(sv[6], sv[7])));
            pm = fmaxf(pm, __shfl_xor(pm, 16));
            pm = fmaxf(pm, __shfl_xor(pm, 32));
            float mnew = fmaxf(mrun[u], pm);
            float pv[8];
#pragma unroll
            for (int j2 = 0; j2 < 8; j2++) pv[j2] = __expf(sv[j2] - mnew);
            float ls = ((pv[0] + pv[1]) + (pv[2] + pv[3]))
                     + ((pv[4] + pv[5]) + (pv[6] + pv[7]));
            ls += __shfl_xor(ls, 16);
            ls += __shfl_xor(ls, 32);
            if (__any(pm > mrun[u])) {      // exact skip: fac==1 for all q otherwise
                float fac = __expf(mrun[u] - mnew);
                float fr[4];
#pragma unroll
                for (int r = 0; r < 4; r++) fr[r] = __shfl(fac, g * 4 + r);
#pragma unroll
                for (int j = 0; j < 3; j++)
#pragma unroll
                    for (int r = 0; r < 4; r++) { o1[u][j][r] *= fr[r]; o2[u][j][r] *= fr[r]; }
                srun[u] = srun[u] * fac + ls;
                mrun[u] = mnew;
            } else {
                srun[u] += ls;
            }
            // split P (pv >= 0: guard without fabs), stage through private LDS
#pragma unroll
            for (int kt2 = 0; kt2 < 2; kt2++) {
                f16x4 hh, llo;
#pragma unroll
                for (int r = 0; r < 4; r++) {
                    float pvv = pv[kt2 * 4 + r];
                    f16 a = (pvv >= 6.103515625e-05f) ? (f16)pvv : (f16)0.f;
                    hh[r] = a;
                    llo[r] = (f16)((pvv - (float)a) * 4096.f);
                }
                *(f16x4*)&Plds[wv][u][0][myq][kt2 * 16 + g * 4] = hh;
                *(f16x4*)&Plds[wv][u][1][myq][kt2 * 16 + g * 4] = llo;
            }
            f16x8 pah = *(const f16x8*)&Plds[wv][u][0][myq][g * 8];
            f16x8 pal = *(const f16x8*)&Plds[wv][u][1][myq][g * 8];
            // PV accumulate
#pragma unroll
            for (int j = 0; j < 3; j++) {
                o1[u][j] = MFMA16(pah, vh[j], o1[u][j]);
                o2[u][j] = MFMA16(pah, vl[j], o2[u][j]);
                o2[u][j] = MFMA16(pal, vh[j], o2[u][j]);
            }
        }
    }
    // epilogue: normalize, split-store to ATT frag planes
#pragma unroll
    for (int u = 0; u < 2; u++) {
        float inv = 1.f / srun[u];
        float ir[4];
#pragma unroll
        for (int r = 0; r < 4; r++) ir[r] = __shfl(inv, g * 4 + r);
#pragma unroll
        for (int j = 0; j < 3; j++) {
            int c = h * D_ + j * 16 + myq;   // col=lane&15=d
#pragma unroll
            for (int r = 0; r < 4; r++) {
                int q = (qt0 + u) * 16 + g * 4 + r;
                if (q >= T_) continue;
                float v = (o1[u][j][r] + o2[u][j][r] * 0.000244140625f) * ir[r];
                int grow = b * T_ + q;
                f16 hv, lv; splitf(v, hv, lv);
                size_t off = afrag(grow, c, 12);
                ap<f16>(ATH_OFF)[off] = hv;
                ap<f16>(ATL_OFF)[off] = lv;
            }
        }
    }
}

// ---------------- ci stage A/B (double)
__global__ __launch_bounds__(384) void cia_kernel()
{
    int b = blockIdx.x, s = blockIdx.y, c = threadIdx.x;
    const float* xm = ap<float>(XM_OFF);
    const int SL = (T_ + 7) / 8;
    int t0 = s * SL, t1 = min(t0 + SL, T_);
    double sm = 0.0;
    for (int t = t0; t < t1; t++) sm += (double)xm[((size_t)b * T_ + t) * C_ + c];
    ap<double>(CIP_OFF)[((size_t)b * 8 + s) * C_ + c] = sm;
}

__global__ __launch_bounds__(384) void cib_kernel()
{
    int b = blockIdx.x, c = threadIdx.x;
    const double* pp = ap<double>(CIP_OFF);
    double sm = 0.0;
#pragma unroll
    for (int s = 0; s < 8; s++) sm += pp[((size_t)b * 8 + s) * C_ + c];
    sm /= (double)T_;
    ap<double>(CID_OFF)[b * C_ + c] = 1.0 / (1.0 + exp(-sm));
}

// ---------------- ca (double), 4 rows per 256-thread block
__global__ __launch_bounds__(256) void ca_kernel()
{
    const float* xres1 = ap<float>(RES_OFF);
    const double* ci   = ap<double>(CID_OFF);
    int idx = blockIdx.x * 4 + (threadIdx.x >> 6);
    int b = idx / HW_, n = idx - b * HW_;
    int lane = threadIdx.x & 63;
    double s = 0.0;
    for (int c = lane; c < C_; c += 64)
        s += (double)xres1[((size_t)b * T_ + 1 + n) * C_ + c] * ci[b * C_ + c];
    for (int o = 32; o; o >>= 1) s += __shfl_down(s, o);
    if (lane == 0) ap<double>(CAD_OFF)[idx] = s;
}

// ---------------- stable rank
__global__ __launch_bounds__(256) void rank_kernel()
{
    const double* ca = ap<double>(CAD_OFF);
    int* perm = ap<int>(PERM_OFF);
    int b = blockIdx.x, tid = threadIdx.x;
    __shared__ double cs[HW_];
    for (int i = tid; i < HW_; i += 256) cs[i] = ca[b * HW_ + i];
    __syncthreads();
    for (int i = tid; i < HW_; i += 256) {
        double vi = cs[i];
        int r = 0;
        for (int j = 0; j < HW_; j++) {
            double vj = cs[j];
            r += (vj < vi) || (vj == vi && j < i);
        }
        if (r >= HW_ - TP_ + 1) perm[b * (TP_ - 1) + (r - (HW_ - TP_ + 1))] = i;
    }
}

// ---------------- LN2 A/B/apply
__global__ __launch_bounds__(256) void ln2a_kernel()
{
    const float* xres1 = ap<float>(RES_OFF);
    const int* perm = ap<int>(PERM_OFF);
    const int TC = TP_ * C_;
    const int SL = (TC + 7) / 8;
    int b = blockIdx.x, s = blockIdx.y, tid = threadIdx.x;
    int e0 = s * SL, e1 = min(e0 + SL, TC);
    __shared__ double r1[256], r2[256];
    double sm = 0.0, s2 = 0.0;
    for (int e = e0 + tid; e < e1; e += 256) {
        int t = e / C_, c = e - t * C_;
        int st = (t == 0) ? 0 : 1 + perm[b * (TP_ - 1) + t - 1];
        double v = (double)xres1[((size_t)b * T_ + st) * C_ + c];
        sm += v; s2 += v * v;
    }
    r1[tid] = sm; r2[tid] = s2; __syncthreads();
    for (int o = 128; o; o >>= 1) {
        if (tid < o) { r1[tid] += r1[tid + o]; r2[tid] += r2[tid + o]; }
        __syncthreads();
    }
    if (tid == 0) {
        double2* ps = ap<double2>(L2PS_OFF);
        ps[b * 8 + s] = make_double2(r1[0], r2[0]);
    }
}

__global__ __launch_bounds__(64) void ln2b_kernel()
{
    int b = blockIdx.x, lane = threadIdx.x;
    const double2* ps = ap<double2>(L2PS_OFF);
    double sm = 0.0, s2 = 0.0;
    if (lane < 8) { sm = ps[b * 8 + lane].x; s2 = ps[b * 8 + lane].y; }
    for (int o = 4; o; o >>= 1) { sm += __shfl_down(sm, o); s2 += __shfl_down(s2, o); }
    if (lane == 0) {
        const int TC = TP_ * C_;
        double m = sm / TC;
        double var = s2 / TC - m * m;
        ap<float>(L2MU_OFF)[b] = (float)m;
        ap<float>(L2RS_OFF)[b] = (float)(1.0 / sqrt(var + 1e-5));
    }
}

__global__ __launch_bounds__(256) void ln2_apply_kernel()
{
    size_t i = (size_t)blockIdx.x * 256 + threadIdx.x;
    if (i >= NX2) return;
    const int TC = TP_ * C_;
    int b = (int)(i / TC);
    int e = (int)(i - (size_t)b * TC);
    int t = e / C_, c = e - t * C_;
    const int* perm = ap<int>(PERM_OFF);
    int st = (t == 0) ? 0 : 1 + perm[b * (TP_ - 1) + t - 1];
    float v = ap<float>(RES_OFF)[((size_t)b * T_ + st) * C_ + c];
    float r = (v - ap<float>(L2MU_OFF)[b]) * ap<float>(L2RS_OFF)[b]
              * ap<float>(LN2W_OFF)[e] + ap<float>(LN2B_OFF)[e];
    ap<float>(X2N_OFF)[i] = r;
    int grow = b * TP_ + t;
    f16 h, l; splitf(r, h, l);
    size_t off = afrag(grow, c, 12);
    ap<f16>(X2NH_OFF)[off] = h;
    ap<f16>(X2NL_OFF)[off] = l;
}

// ---------------- FFN2 reduce: 2 split-K partials + x2n resid -> split store
__global__ __launch_bounds__(256) void ffn2_reduce_kernel(float* __restrict__ out)
{
    const size_t tot = NX2;
    size_t i = (size_t)blockIdx.x * 256 + threadIdx.x;
    if (i >= tot) return;
    const float* part = ap<float>(PART_OFF);
    float v = part[i] + part[tot + i] + ap<float>(X2N_OFF)[i];
    int gm = (int)(i / C_);
    int gn = (int)(i - (size_t)gm * C_);
    int b = gm / TP_, t = gm - b * TP_;
    size_t off = (t == 0)
        ? ((size_t)B_ * (TP_ - 1) * C_ + (size_t)b * C_ + gn)
        : ((size_t)(b * (TP_ - 1) + (t - 1)) * C_ + gn);
    out[off] = v;
}

extern "C" void kernel_launch(void* const* d_in, const int* in_sizes, int n_in,
                              void* d_out, int out_size, void* d_ws, size_t ws_size,
                              hipStream_t stream)
{
    float* out = (float*)d_out;
    (void)d_ws; (void)ws_size; (void)in_sizes; (void)n_in; (void)out_size;

    const int M1 = B_ * T_;            // 25120
    const int M2 = B_ * TP_;           // 6304

    // 0. dtype detect + merged conversion + weight frag repack
    detect_kernel<<<1, 64, 0, stream>>>((const unsigned*)d_in[2]);
    SrcPtrs sp;
    for (int i = 0; i < 12; i++) sp.p[i] = d_in[i];
    cvt_all_kernel<<<(int)((NTOT_CVT + 255) / 256), 256, 0, stream>>>(sp);
    wrepack_kernel<<<(int)((4 * NWP + 2 * NW1 + 255) / 256), 256, 0, stream>>>();

    // 1. LN1 (emits X1 frag planes)
    stats1a_kernel<<<dim3(B_, 16), 256, 0, stream>>>();
    stats1b_kernel<<<B_, 64, 0, stream>>>();
    ln1_apply_kernel<<<(int)((NRES + 255) / 256), 256, 0, stream>>>();

    // 2. merged QKV projection (direct-frag MFMA -> Q/K/V frag planes)
    gemm_fd<5><<<dim3(197 * 9), 256, 0, stream>>>(
        X1H_OFF, X1L_OFF, WPH_OFF, WPL_OFF, 0, M1, 3 * C_, 12, 9);

    // 3. fused flash attention (q-batch x2, bh-major XCD-local grid)
    flash_kernel<<<dim3(256 * 7), 256, 0, stream>>>();

    // Wo projection fused with residual (B = tiles 72..95 of WQKVO frag pack)
    gemm_fd<4><<<dim3(197 * 3), 256, 0, stream>>>(
        ATH_OFF, ATL_OFF,
        WPH_OFF + (size_t)442368 * 2, WPL_OFF + (size_t)442368 * 2,
        XM_OFF, M1, C_, 12, 3);

    // 4. ci, ca, rank, LN2 (fp32/fp64 ordering path unchanged)
    cia_kernel<<<dim3(B_, 8), 384, 0, stream>>>();
    cib_kernel<<<B_, 384, 0, stream>>>();
    ca_kernel<<<B_ * HW_ / 4, 256, 0, stream>>>();
    rank_kernel<<<B_, 256, 0, stream>>>();
    ln2a_kernel<<<dim3(B_, 8), 256, 0, stream>>>();
    ln2b_kernel<<<B_, 64, 0, stream>>>();
    ln2_apply_kernel<<<(int)((NX2 + 255) / 256), 256, 0, stream>>>();

    // 5. FFN: gelu GEMM -> H frag, split-K=2 GEMM + reduce
    gemm_fd<2><<<dim3(50 * 12), 256, 0, stream>>>(
        X2NH_OFF, X2NL_OFF, WFH_OFF, WFL_OFF, 0, M2, FF_, 12, 12);
    gemm_fd<6><<<dim3(50 * 3, 1, 2), 256, 0, stream>>>(
        HFH_OFF, HFL_OFF, WFH_OFF + NW1 * 2, WFL_OFF + NW1 * 2, 0, M2, C_, 48, 3);
    ffn2_reduce_kernel<<<(int)((NX2 + 255) / 256), 256, 0, stream>>>(out);
}